// Round 1
// baseline (1156.897 us; speedup 1.0000x reference)
//
#include <hip/hip_runtime.h>
#include <hip/hip_bf16.h>

#define B_SZ 32
#define NSEQ 4096
#define DM   1024
#define NH   16

typedef __attribute__((ext_vector_type(8))) short bf16x8;
typedef __attribute__((ext_vector_type(4))) float f32x4;

// fp32 -> bf16 bits with round-to-nearest-even (manual, 3 VALU ops)
__device__ __forceinline__ short f2bf(float f) {
  unsigned int x = __float_as_uint(f);
  unsigned int r = (x + 0x7fffu + ((x >> 16) & 1u)) >> 16;
  return (short)r;
}

// Pass 0: qw[b,h,D] = (1/8) * sum_d (query[b,:]·wq[:,h*64+d]) * wk[D, h*64+d]
// grid: 512 blocks (b*16+h), 64 threads
__global__ __launch_bounds__(64) void qw_kernel(
    const float* __restrict__ query, const float* __restrict__ wq,
    const float* __restrict__ wk, short* __restrict__ qw16) {
  int b = blockIdx.x >> 4, h = blockIdx.x & 15;
  int t = threadIdx.x;  // 0..63
  __shared__ float qs[DM];
  __shared__ float qh[64];
  const f32x4* q4 = (const f32x4*)(query + (size_t)b * DM);
  f32x4* qs4 = (f32x4*)qs;
  for (int i = t; i < DM / 4; i += 64) qs4[i] = q4[i];
  __syncthreads();
  // q[d=t] = query[b,:] · wq[:, h*64+t]   (coalesced across t)
  float acc = 0.f;
  const float* wqc = wq + h * 64 + t;
  #pragma unroll 8
  for (int D = 0; D < DM; ++D) acc += qs[D] * wqc[(size_t)D * DM];
  qh[t] = acc * 0.125f;  // fold 1/sqrt(64) scale here
  __syncthreads();
  // qw[D] = sum_d qh[d] * wk[D, h*64+d]; each thread does 16 D-rows
  for (int k = 0; k < 16; ++k) {
    int D = t + 64 * k;
    const f32x4* wk4 = (const f32x4*)(wk + (size_t)D * DM + h * 64);
    float a = 0.f;
    #pragma unroll
    for (int j = 0; j < 16; ++j) {
      f32x4 w = wk4[j];
      a += qh[j * 4 + 0] * w[0] + qh[j * 4 + 1] * w[1] +
           qh[j * 4 + 2] * w[2] + qh[j * 4 + 3] * w[3];
    }
    qw16[((size_t)b * NH + h) * DM + D] = f2bf(a);
  }
}

// Pass A: scores[b,h,n] = key[b,n,:] · qw[b,h,:]
// grid: 2048 blocks (b*64 + ngroup), 256 threads = 4 waves, wave = 16 n-rows
__global__ __launch_bounds__(256) void scores_kernel(
    const float* __restrict__ key, const short* __restrict__ qw16,
    float* __restrict__ scores) {
  int blk = blockIdx.x;
  int b  = blk >> 6;
  int ng = blk & 63;
  int wave = threadIdx.x >> 6;
  int lane = threadIdx.x & 63;
  int quad = lane >> 4;
  int lm   = lane & 15;
  int n0 = ng * 64 + wave * 16;
  // A: key rows (m = n), B: qw rows (col = h), both k = quad*8 + j
  const float* ka = key  + ((size_t)b * NSEQ + n0 + lm) * DM + quad * 8;
  const short* bb = qw16 + ((size_t)b * NH   + lm) * DM + quad * 8;
  f32x4 acc = {0.f, 0.f, 0.f, 0.f};
  #pragma unroll 4
  for (int kc = 0; kc < 32; ++kc) {
    f32x4 a0 = *(const f32x4*)(ka + kc * 32);
    f32x4 a1 = *(const f32x4*)(ka + kc * 32 + 4);
    bf16x8 bfrag = *(const bf16x8*)(bb + kc * 32);
    bf16x8 afrag;
    afrag[0] = f2bf(a0[0]); afrag[1] = f2bf(a0[1]);
    afrag[2] = f2bf(a0[2]); afrag[3] = f2bf(a0[3]);
    afrag[4] = f2bf(a1[0]); afrag[5] = f2bf(a1[1]);
    afrag[6] = f2bf(a1[2]); afrag[7] = f2bf(a1[3]);
    acc = __builtin_amdgcn_mfma_f32_16x16x32_bf16(afrag, bfrag, acc, 0, 0, 0);
  }
  // D: row(n-offset) = quad*4 + r, col(h) = lm -> 4 consecutive n per lane
  size_t sidx = ((size_t)b * NH + lm) * NSEQ + n0 + quad * 4;
  *(f32x4*)(scores + sidx) = acc;
}

// Pass B: row softmax over N=4096, output bf16 P[b,h,n]
// grid: 512 blocks (b*16+h), 256 threads
__global__ __launch_bounds__(256) void softmax_kernel(
    const float* __restrict__ scores, short* __restrict__ P) {
  int bh = blockIdx.x;
  int t = threadIdx.x;
  int lane = t & 63, wave = t >> 6;
  const f32x4* row = (const f32x4*)(scores + (size_t)bh * NSEQ);
  f32x4 v[4];
  float m = -1e30f;
  #pragma unroll
  for (int i = 0; i < 4; ++i) {
    v[i] = row[t + 256 * i];
    m = fmaxf(m, fmaxf(fmaxf(v[i][0], v[i][1]), fmaxf(v[i][2], v[i][3])));
  }
  #pragma unroll
  for (int off = 32; off > 0; off >>= 1) m = fmaxf(m, __shfl_xor(m, off));
  __shared__ float sm[4], ss[4];
  if (lane == 0) sm[wave] = m;
  __syncthreads();
  m = fmaxf(fmaxf(sm[0], sm[1]), fmaxf(sm[2], sm[3]));
  float s = 0.f;
  #pragma unroll
  for (int i = 0; i < 4; ++i)
    #pragma unroll
    for (int j = 0; j < 4; ++j) { v[i][j] = __expf(v[i][j] - m); s += v[i][j]; }
  #pragma unroll
  for (int off = 32; off > 0; off >>= 1) s += __shfl_xor(s, off);
  if (lane == 0) ss[wave] = s;
  __syncthreads();
  float inv = 1.f / (ss[0] + ss[1] + ss[2] + ss[3]);
  short* Pr = P + (size_t)bh * NSEQ;
  #pragma unroll
  for (int i = 0; i < 4; ++i) {
    short4 p;
    p.x = f2bf(v[i][0] * inv); p.y = f2bf(v[i][1] * inv);
    p.z = f2bf(v[i][2] * inv); p.w = f2bf(v[i][3] * inv);
    *(short4*)(Pr + (size_t)(t + 256 * i) * 4) = p;
  }
}

// Pass C: ctx_partial[ns][b][h][D] = sum_{n in split} P[b,h,n] * value[b,n,D]
// grid: 2048 blocks ((b*16 + Dg)*4 + ns), 256 threads = 4 waves (adjacent D-tiles)
__global__ __launch_bounds__(256) void ctx_kernel(
    const float* __restrict__ value, const short* __restrict__ P,
    float* __restrict__ ctxp) {
  int blk = blockIdx.x;
  int ns = blk & 3;
  int Dg = (blk >> 2) & 15;
  int b  = blk >> 6;
  int wave = threadIdx.x >> 6, lane = threadIdx.x & 63;
  int quad = lane >> 4, lm = lane & 15;
  int col = Dg * 64 + wave * 16 + lm;   // D column
  int n0 = ns * 1024;
  // A: P rows (m = h, k = n), B: value (k = n row, col = D)
  const short* pa = P + ((size_t)b * NH + lm) * NSEQ + n0 + quad * 8;
  const float* vb = value + ((size_t)b * NSEQ + n0 + quad * 8) * DM + col;
  f32x4 acc = {0.f, 0.f, 0.f, 0.f};
  #pragma unroll 2
  for (int kc = 0; kc < 32; ++kc) {
    bf16x8 afrag = *(const bf16x8*)(pa + kc * 32);
    const float* vp = vb + (size_t)kc * 32 * DM;
    bf16x8 bfrag;
    #pragma unroll
    for (int j = 0; j < 8; ++j) bfrag[j] = f2bf(vp[(size_t)j * DM]);
    acc = __builtin_amdgcn_mfma_f32_16x16x32_bf16(afrag, bfrag, acc, 0, 0, 0);
  }
  #pragma unroll
  for (int r = 0; r < 4; ++r) {
    int h = quad * 4 + r;
    ctxp[(((size_t)ns * B_SZ + b) * NH + h) * DM + col] = acc[r];
  }
}

// Pass D: out[b, h*64+d] = sum_D (sum_ns ctxp[ns,b,h,D]) * wv[D, h*64+d]
// grid: 512 blocks (b*16+h), 256 threads
__global__ __launch_bounds__(256) void out_kernel(
    const float* __restrict__ ctxp, const float* __restrict__ wv,
    float* __restrict__ out) {
  int b = blockIdx.x >> 4, h = blockIdx.x & 15;
  int t = threadIdx.x;
  __shared__ float ctx[DM];
  for (int i = t; i < DM; i += 256) {
    float s = 0.f;
    #pragma unroll
    for (int ns = 0; ns < 4; ++ns)
      s += ctxp[(((size_t)ns * B_SZ + b) * NH + h) * DM + i];
    ctx[i] = s;
  }
  __syncthreads();
  int d = t & 63, q = t >> 6;
  float acc = 0.f;
  #pragma unroll 4
  for (int D = q * 256; D < (q + 1) * 256; ++D)
    acc += ctx[D] * wv[(size_t)D * DM + h * 64 + d];
  __shared__ float red[256];
  red[t] = acc;
  __syncthreads();
  if (t < 64)
    out[(size_t)b * DM + h * 64 + t] =
        red[t] + red[t + 64] + red[t + 128] + red[t + 192];
}

extern "C" void kernel_launch(void* const* d_in, const int* in_sizes, int n_in,
                              void* d_out, int out_size, void* d_ws, size_t ws_size,
                              hipStream_t stream) {
  const float* query = (const float*)d_in[0];
  const float* key   = (const float*)d_in[1];
  const float* value = (const float*)d_in[2];
  const float* wq    = (const float*)d_in[3];
  const float* wk    = (const float*)d_in[4];
  const float* wv    = (const float*)d_in[5];
  float* out = (float*)d_out;
  char* ws = (char*)d_ws;

  short* qw16   = (short*)(ws);                    // 1 MiB: [32][16][1024] bf16
  float* scores = (float*)(ws + (1u << 20));       // 8 MiB: [32][16][4096] f32
  short* P      = (short*)(ws + (9u << 20));       // 4 MiB: [32][16][4096] bf16
  float* ctxp   = (float*)(ws + (13u << 20));      // 8 MiB: [4][32][16][1024] f32

  qw_kernel     <<<B_SZ * NH, 64,  0, stream>>>(query, wq, wk, qw16);
  scores_kernel <<<B_SZ * 64, 256, 0, stream>>>(key, qw16, scores);
  softmax_kernel<<<B_SZ * NH, 256, 0, stream>>>(scores, P);
  ctx_kernel    <<<B_SZ * 64, 256, 0, stream>>>(value, P, ctxp);
  out_kernel    <<<B_SZ * NH, 256, 0, stream>>>(ctxp, wv, out);
}